// Round 1
// baseline (188.015 us; speedup 1.0000x reference)
//
#include <hip/hip_runtime.h>

#define BB 8192
#define TT 512
#define II 5
#define HH 16
#define TC 64
#define NCHUNK (TT / TC)

__device__ __forceinline__ float dot4(float4 a, float4 b, float acc) {
    acc = fmaf(a.x, b.x, acc);
    acc = fmaf(a.y, b.y, acc);
    acc = fmaf(a.z, b.z, acc);
    acc = fmaf(a.w, b.w, acc);
    return acc;
}

__device__ __forceinline__ float fast_sigmoid(float x) {
    // 1 / (1 + e^{-x});  e^{-x} = exp2(-x * log2(e))
    float e = __builtin_amdgcn_exp2f(x * -1.4426950408889634f);
    return __builtin_amdgcn_rcpf(1.0f + e);
}

__device__ __forceinline__ float fast_tanh(float x) {
    // 1 - 2/(e^{2x} + 1)
    float e = __builtin_amdgcn_exp2f(x * 2.8853900817779268f);
    return fmaf(-2.0f, __builtin_amdgcn_rcpf(e + 1.0f), 1.0f);
}

__global__ __launch_bounds__(256, 2)
void gru_fwd_kernel(const float* __restrict__ x,
                    const float* __restrict__ W_ih,
                    const float* __restrict__ W_hh,
                    const float* __restrict__ b_ih,
                    const float* __restrict__ b_hh,
                    const float* __restrict__ W_fc,
                    const float* __restrict__ b_fc,
                    float* __restrict__ out) {
    // LDS: x chunk (padded to dodge bank conflicts) + h broadcast buffer
    __shared__ float4 lds_x4[16][TC + 1];   // x[b][t][0:4]
    __shared__ float  lds_x1[16][TC + 8];   // x[b][t][4]
    __shared__ float  lds_h [16][20];       // h broadcast, 20-float stride -> 2-way max

    const int tid = threadIdx.x;
    const int g   = tid >> 4;    // group (local batch) 0..15
    const int j   = tid & 15;    // h index 0..15
    const int b0  = blockIdx.x * 16;
    const int b   = b0 + g;

    // ---- load weights into registers (uniform per lane-j, one-time) ----
    const float* wrp = W_hh + (size_t)j * HH;          // reset row
    const float* wzp = W_hh + (size_t)(HH + j) * HH;   // update row
    const float* wnp = W_hh + (size_t)(2 * HH + j) * HH; // candidate row
    float4 whr0 = ((const float4*)wrp)[0], whr1 = ((const float4*)wrp)[1],
           whr2 = ((const float4*)wrp)[2], whr3 = ((const float4*)wrp)[3];
    float4 whz0 = ((const float4*)wzp)[0], whz1 = ((const float4*)wzp)[1],
           whz2 = ((const float4*)wzp)[2], whz3 = ((const float4*)wzp)[3];
    float4 whn0 = ((const float4*)wnp)[0], whn1 = ((const float4*)wnp)[1],
           whn2 = ((const float4*)wnp)[2], whn3 = ((const float4*)wnp)[3];

    const float* irp = W_ih + (size_t)j * II;
    const float* izp = W_ih + (size_t)(HH + j) * II;
    const float* inp = W_ih + (size_t)(2 * HH + j) * II;
    float4 wir = make_float4(irp[0], irp[1], irp[2], irp[3]); float wir4 = irp[4];
    float4 wiz = make_float4(izp[0], izp[1], izp[2], izp[3]); float wiz4 = izp[4];
    float4 win = make_float4(inp[0], inp[1], inp[2], inp[3]); float win4 = inp[4];

    const float brz = b_ih[j] + b_hh[j];                 // r-gate bias (combined)
    const float bzz = b_ih[HH + j] + b_hh[HH + j];       // z-gate bias (combined)
    const float bxn = b_ih[2 * HH + j];                  // n-gate input-side bias
    const float bhn = b_hh[2 * HH + j];                  // n-gate hidden-side bias

    float h = 0.0f;

    const float* xblk = x + (size_t)b0 * (TT * II);

    for (int c = 0; c < NCHUNK; ++c) {
        const int t0 = c * TC;
        __syncthreads();  // previous chunk's inner-loop reads are done
        // ---- stage x[b0:b0+16, t0:t0+TC, :] into LDS (coalesced) ----
        #pragma unroll
        for (int it = 0; it < (16 * TC * II) / 256; ++it) {
            int f  = tid + it * 256;
            int bl = f / (TC * II);
            int r  = f - bl * (TC * II);
            float v = xblk[(size_t)bl * (TT * II) + (size_t)t0 * II + r];
            int t  = r / II;
            int i  = r - t * II;
            if (i < 4) ((float*)&lds_x4[bl][t])[i] = v;
            else       lds_x1[bl][t] = v;
        }
        __syncthreads();

        // ---- 64 recurrence steps ----
        for (int s = 0; s < TC; ++s) {
            // broadcast h within the 16-lane group (wave-local, DS in-order)
            lds_h[g][j] = h;
            const float4* hp = (const float4*)&lds_h[g][0];
            float4 h0 = hp[0], h1 = hp[1], h2 = hp[2], h3 = hp[3];

            float ar  = brz, az = bzz, anh = bhn, anx = bxn;
            ar  = dot4(whr0, h0, ar );  ar  = dot4(whr1, h1, ar );
            ar  = dot4(whr2, h2, ar );  ar  = dot4(whr3, h3, ar );
            az  = dot4(whz0, h0, az );  az  = dot4(whz1, h1, az );
            az  = dot4(whz2, h2, az );  az  = dot4(whz3, h3, az );
            anh = dot4(whn0, h0, anh);  anh = dot4(whn1, h1, anh);
            anh = dot4(whn2, h2, anh);  anh = dot4(whn3, h3, anh);

            float4 xv = lds_x4[g][s];
            float  xe = lds_x1[g][s];
            ar  = dot4(wir, xv, ar );  ar  = fmaf(wir4, xe, ar );
            az  = dot4(wiz, xv, az );  az  = fmaf(wiz4, xe, az );
            anx = dot4(win, xv, anx);  anx = fmaf(win4, xe, anx);

            float r = fast_sigmoid(ar);
            float z = fast_sigmoid(az);
            float n = fast_tanh(fmaf(r, anh, anx));
            h = fmaf(z, h - n, n);   // (1-z)*n + z*h
        }
    }

    // ---- output: out[b] = dot(W_fc, h) + b_fc ----
    float w = h * W_fc[j];
    w += __shfl_xor(w, 1);
    w += __shfl_xor(w, 2);
    w += __shfl_xor(w, 4);
    w += __shfl_xor(w, 8);
    if (j == 0) out[b] = w + b_fc[0];
}

extern "C" void kernel_launch(void* const* d_in, const int* in_sizes, int n_in,
                              void* d_out, int out_size, void* d_ws, size_t ws_size,
                              hipStream_t stream) {
    const float* x    = (const float*)d_in[0];
    const float* W_ih = (const float*)d_in[1];
    const float* W_hh = (const float*)d_in[2];
    const float* b_ih = (const float*)d_in[3];
    const float* b_hh = (const float*)d_in[4];
    const float* W_fc = (const float*)d_in[5];
    const float* b_fc = (const float*)d_in[6];
    float* out = (float*)d_out;

    dim3 grid(BB / 16);
    dim3 block(256);
    gru_fwd_kernel<<<grid, block, 0, stream>>>(x, W_ih, W_hh, b_ih, b_hh, W_fc, b_fc, out);
}